// Round 6
// baseline (149.371 us; speedup 1.0000x reference)
//
#include <hip/hip_runtime.h>
#include <hip/hip_bf16.h>

// FenwickLogLinearAttention: B=2,T=2048,C=1024,H=16,Dh=64
// R9: qkv back to the PROVEN m97 configuration: 128x128 tile, BK=64, 256 thr,
//     single-buffered 32KB LDS, plain 2-syncthreads K-loop — but now at
//     3 blocks/CU (launch_bounds(256,4), grid 768) AND with XCD region swizzle
//     (8 rowblk x 12 colblk per XCD: A 2MB + B 3MB ~ L2-resident).
//     R4-R8 taught: 1-block/CU mega-tile removes the cross-block TLP that
//     m97/m102 relied on; no schedule variant substitutes for it at K=1024.
//     proj (dbuf, 1 sync/tile) / attn / prep unchanged from R8.
// ws layout (bytes): xb@0 (8M) | WqkvT@8M (6M) | QKVb@14M (24M) | AO@38M (8M) | WprojT@46M (2M)

typedef unsigned short ushort_t;
typedef __attribute__((ext_vector_type(8))) short s16x8;
typedef __attribute__((ext_vector_type(4))) float f32x4;

#define T_SEQ 2048
#define C_DIM 1024
#define HEADS 16

__device__ __forceinline__ ushort_t f2bf(float f) {
    union { float f; unsigned u; } v{f};
    unsigned r = v.u + 0x7FFFu + ((v.u >> 16) & 1u);   // RNE
    return (ushort_t)(r >> 16);
}
__device__ __forceinline__ float bf2f(ushort_t u) {
    union { unsigned u; float f; } v{((unsigned)u) << 16};
    return v.f;
}

__device__ __forceinline__ void async16(const ushort_t* g, ushort_t* l) {
    __builtin_amdgcn_global_load_lds(
        (const __attribute__((address_space(1))) void*)g,
        (__attribute__((address_space(3))) void*)l, 16, 0, 0);
}

// ---------------- merged prep: cvt(x)->bf16 + two weight transposes ----------------
__global__ void prep(const float* __restrict__ x, ushort_t* __restrict__ xb,
                     const float* __restrict__ Wq, ushort_t* __restrict__ WqT,
                     const float* __restrict__ Wp, ushort_t* __restrict__ WpT) {
    const int bid = blockIdx.x;
    const int tid = threadIdx.x;
    if (bid < 4096) {
        const int i = bid * 256 + tid;
        float4 f = ((const float4*)x)[i];
        ushort4 o;
        o.x = f2bf(f.x); o.y = f2bf(f.y); o.z = f2bf(f.z); o.w = f2bf(f.w);
        ((ushort4*)xb)[i] = o;
    } else {
        __shared__ ushort_t tile[32][33];
        const float* W; ushort_t* WT; int N, nb, kb;
        if (bid < 7168) {
            const int tb = bid - 4096;
            W = Wq; WT = WqT; N = 3072; nb = (tb % 96) * 32; kb = (tb / 96) * 32;
        } else {
            const int tb = bid - 7168;
            W = Wp; WT = WpT; N = 1024; nb = (tb & 31) * 32; kb = (tb >> 5) * 32;
        }
        const int tx = tid & 31, ty = tid >> 5;
        #pragma unroll
        for (int i = ty; i < 32; i += 8)
            tile[i][tx] = f2bf(W[(size_t)(kb + i) * N + nb + tx]);
        __syncthreads();
        #pragma unroll
        for (int i = ty; i < 32; i += 8)
            WT[(size_t)(nb + i) * 1024 + kb + tx] = tile[tx][i];
    }
}

// ---------------- QKV GEMM: 128x128 tile, BK=64, m97 structure, 3 blocks/CU ----------------
// C[M][N] = A[M][K] @ BT[N][K]^T + bias[N], bf16 out.
// Grid 768 (1D): XCD (bid&7) owns an 8-rowblk x 12-colblk region
// (A 1024 rows x 2KB = 2MB + B 1536 cols x 2KB = 3MB ~ L2-resident).
// LDS: single-buffered 2 x 16KB; swizzled k-groups (slot s of row r holds
// global k-group s ^ (r&7)); plain 2-syncthreads loop — cross-block TLP
// (3 blocks/CU) does the latency hiding (m97/m114).
__global__ __launch_bounds__(256, 4)
void gemm_qkv(const ushort_t* __restrict__ A, const ushort_t* __restrict__ BT,
              const float* __restrict__ bias, ushort_t* __restrict__ C,
              int N, int K) {
    __shared__ ushort_t lsA[128 * 64];
    __shared__ ushort_t lsB[128 * 64];

    const int tid  = threadIdx.x;
    const int wave = tid >> 6;
    const int lane = tid & 63;

    const int bid    = blockIdx.x;
    const int xcd    = bid & 7;
    const int q      = bid >> 3;                    // [0,96)
    const int rowblk = ((xcd & 3) << 3) + (q & 7);  // [0,32)
    const int colblk = (xcd >> 2) * 12 + (q >> 3);  // [0,24)
    const int row0   = rowblk * 128;
    const int col0   = colblk * 128;

    const int wr   = (wave >> 1) * 64;
    const int wc   = (wave & 1) * 64;
    const int lrow = lane & 15;
    const int quad = lane >> 4;
    const int crow = lane >> 3;                // staging: row within 8-row chunk
    const int gcol = ((lane & 7) ^ crow) * 8;  // swizzled global k-group fetched
    const int d3   = lrow & 7;                 // read-side swizzle key

    f32x4 acc[4][4] = {};

    for (int k0 = 0; k0 < K; k0 += 64) {
        #pragma unroll
        for (int it = 0; it < 4; ++it) {
            const int chunk = it * 4 + wave;           // 16 chunks x 1KB
            const int r = chunk * 8 + crow;
            async16(A  + (size_t)(row0 + r) * K + (k0 + gcol), lsA + chunk * 512);
            async16(BT + (size_t)(col0 + r) * K + (k0 + gcol), lsB + chunk * 512);
        }
        __syncthreads();   // drains vmcnt -> staged data visible
        #pragma unroll
        for (int kk = 0; kk < 64; kk += 32) {
            const int g = (kk >> 3) + quad;            // desired k-group
            const int slot = (g ^ d3) << 3;            // swizzled LDS slot
            s16x8 af[4], bfr[4];
            #pragma unroll
            for (int i = 0; i < 4; ++i)
                af[i] = *(const s16x8*)(lsA + (wr + i * 16 + lrow) * 64 + slot);
            #pragma unroll
            for (int j = 0; j < 4; ++j)
                bfr[j] = *(const s16x8*)(lsB + (wc + j * 16 + lrow) * 64 + slot);
            #pragma unroll
            for (int i = 0; i < 4; ++i)
                #pragma unroll
                for (int j = 0; j < 4; ++j)
                    acc[i][j] = __builtin_amdgcn_mfma_f32_16x16x32_bf16(
                        af[i], bfr[j], acc[i][j], 0, 0, 0);
        }
        __syncthreads();
    }

    // D mapping: col=lane&15, row=quad*4+reg (m89-verified)
    #pragma unroll
    for (int i = 0; i < 4; ++i) {
        #pragma unroll
        for (int j = 0; j < 4; ++j) {
            const int col = col0 + wc + j * 16 + lrow;
            const float bv = bias[col];
            #pragma unroll
            for (int r = 0; r < 4; ++r) {
                const int row = row0 + wr + i * 16 + quad * 4 + r;
                C[(size_t)row * N + col] = f2bf(acc[i][j][r] + bv);
            }
        }
    }
}

// ---------------- proj GEMM: 128x128 tile, BK=64, DOUBLE-buffered, 1 sync/tile ----------------
#define PSTAGE(t, b) do {                                                        \
    _Pragma("unroll") for (int it = 0; it < 4; ++it) {                           \
        const int chunk = it * 4 + wave;                                         \
        const int r = chunk * 8 + crow;                                          \
        async16(A  + (size_t)(row0 + r) * K + ((t) * 64 + gcol), lsA[b] + chunk * 512); \
        async16(BT + (size_t)(col0 + r) * K + ((t) * 64 + gcol), lsB[b] + chunk * 512); \
    }                                                                            \
} while (0)

__global__ void gemm_proj(const ushort_t* __restrict__ A, const ushort_t* __restrict__ BT,
                          const float* __restrict__ bias, float* __restrict__ C,
                          int N, int K) {
    __shared__ ushort_t lsA[2][128 * 64];
    __shared__ ushort_t lsB[2][128 * 64];

    const int tid  = threadIdx.x;
    const int wave = tid >> 6;
    const int lane = tid & 63;

    const int bid  = blockIdx.x;
    const int xcd  = bid & 7;
    const int q    = bid >> 3;                 // [0,32)
    const int row0 = (xcd * 4 + (q & 3)) * 128;   // rowblk [0,32)
    const int col0 = (q >> 2) * 128;              // colblk [0,8)

    const int wr   = (wave >> 1) * 64;
    const int wc   = (wave & 1) * 64;
    const int lrow = lane & 15;
    const int quad = lane >> 4;
    const int crow = lane >> 3;
    const int gcol = ((lane & 7) ^ crow) * 8;
    const int d3   = lrow & 7;

    f32x4 acc[4][4] = {};

    const int nt = K >> 6;                     // 16 K-tiles
    int cur = 0;
    PSTAGE(0, 0);
    __syncthreads();                            // drains vmcnt -> tile0 visible
    for (int t = 0; t < nt; ++t) {
        if (t + 1 < nt) PSTAGE(t + 1, cur ^ 1); // overlaps compute below
        #pragma unroll
        for (int kk = 0; kk < 64; kk += 32) {
            const int g = (kk >> 3) + quad;
            const int slot = (g ^ d3) << 3;
            s16x8 af[4], bfr[4];
            #pragma unroll
            for (int i = 0; i < 4; ++i)
                af[i] = *(const s16x8*)(lsA[cur] + (wr + i * 16 + lrow) * 64 + slot);
            #pragma unroll
            for (int j = 0; j < 4; ++j)
                bfr[j] = *(const s16x8*)(lsB[cur] + (wc + j * 16 + lrow) * 64 + slot);
            #pragma unroll
            for (int i = 0; i < 4; ++i)
                #pragma unroll
                for (int j = 0; j < 4; ++j)
                    acc[i][j] = __builtin_amdgcn_mfma_f32_16x16x32_bf16(
                        af[i], bfr[j], acc[i][j], 0, 0, 0);
        }
        __syncthreads();                        // one barrier per tile
        cur ^= 1;
    }

    #pragma unroll
    for (int i = 0; i < 4; ++i) {
        #pragma unroll
        for (int j = 0; j < 4; ++j) {
            const int col = col0 + wc + j * 16 + lrow;
            const float bv = bias[col];
            #pragma unroll
            for (int r = 0; r < 4; ++r) {
                const int row = row0 + wr + i * 16 + quad * 4 + r;
                C[(size_t)row * N + col] = acc[i][j][r] + bv;
            }
        }
    }
}

// ---------------- sparse Fenwick attention ----------------
// bh-per-XCD swizzle: XCD x serves bh in {x, x+8, x+16, x+24} (64 blocks each);
// per-XCD K/V working set = 4 x 512KB = 2MB < 4MB L2.
__global__ void fenwick_attn(const ushort_t* __restrict__ QKV, ushort_t* __restrict__ AO) {
    const int lane = threadIdx.x & 63;
    const int bid  = blockIdx.x;
    const int xcd  = bid & 7;
    const int q    = bid >> 3;                       // [0,256)
    const int bh   = xcd + ((q >> 6) << 3);          // [0,32)
    const int tile = ((q & 63) << 2) + (threadIdx.x >> 6); // [0,256)
    const int h    = bh & (HEADS - 1);
    const int b    = bh >> 4;
    const int tl   = lane >> 3;
    const int g    = lane & 7;
    const int t    = tile * 8 + tl;

    const ushort_t* base = QKV + (size_t)(b * T_SEQ) * 3072 + h * 64 + g * 8;

    float qf[8];
    {
        s16x8 qv = *(const s16x8*)(base + (size_t)t * 3072);
        #pragma unroll
        for (int e = 0; e < 8; ++e) qf[e] = bf2f((ushort_t)qv[e]);
    }

    float logit[12];
    int   pos[12];
    float mx = -1e30f;
    #pragma unroll
    for (int s = 0; s < 12; ++s) {
        const int step = (s == 0) ? 0 : (1 << (s - 1));
        const bool act = (step <= t);
        const int p = act ? (t - step) : t;
        pos[s] = p;
        s16x8 kv = *(const s16x8*)(base + (size_t)p * 3072 + 1024);
        float l = 0.f;
        #pragma unroll
        for (int e = 0; e < 8; ++e) l = fmaf(qf[e], bf2f((ushort_t)kv[e]), l);
        l += __shfl_xor(l, 1, 64);
        l += __shfl_xor(l, 2, 64);
        l += __shfl_xor(l, 4, 64);
        l *= 0.125f;                       // Dh^-0.5
        logit[s] = act ? l : -1e30f;
        mx = fmaxf(mx, logit[s]);
    }

    float denom = 0.f;
    float ov[8] = {};
    #pragma unroll
    for (int s = 0; s < 12; ++s) {
        const float w = __expf(logit[s] - mx);
        denom += w;
        s16x8 vv = *(const s16x8*)(base + (size_t)pos[s] * 3072 + 2048);
        #pragma unroll
        for (int e = 0; e < 8; ++e) ov[e] = fmaf(w, bf2f((ushort_t)vv[e]), ov[e]);
    }

    const float inv = 1.f / denom;
    s16x8 os;
    #pragma unroll
    for (int e = 0; e < 8; ++e) os[e] = (short)f2bf(ov[e] * inv);
    *(s16x8*)(AO + (size_t)(b * T_SEQ + t) * C_DIM + h * 64 + g * 8) = os;
}

extern "C" void kernel_launch(void* const* d_in, const int* in_sizes, int n_in,
                              void* d_out, int out_size, void* d_ws, size_t ws_size,
                              hipStream_t stream) {
    const float* x      = (const float*)d_in[0];
    const float* W_qkv  = (const float*)d_in[1];
    const float* b_qkv  = (const float*)d_in[2];
    const float* W_proj = (const float*)d_in[3];
    const float* b_proj = (const float*)d_in[4];
    float* out = (float*)d_out;

    char* ws = (char*)d_ws;
    ushort_t* xb     = (ushort_t*)(ws);                        // 4096x1024 bf16
    ushort_t* WqkvT  = (ushort_t*)(ws + (size_t)8  * 1048576); // 3072x1024 bf16
    ushort_t* QKVb   = (ushort_t*)(ws + (size_t)14 * 1048576); // 4096x3072 bf16
    ushort_t* AO     = (ushort_t*)(ws + (size_t)38 * 1048576); // 4096x1024 bf16
    ushort_t* WprojT = (ushort_t*)(ws + (size_t)46 * 1048576); // 1024x1024 bf16

    prep<<<8192, 256, 0, stream>>>(x, xb, W_qkv, WqkvT, W_proj, WprojT);
    gemm_qkv<<<768, 256, 0, stream>>>(xb, WqkvT, b_qkv, QKVb, 3072, 1024);
    fenwick_attn<<<2048, 256, 0, stream>>>(QKVb, AO);
    gemm_proj<<<256, 256, 0, stream>>>(AO, WprojT, b_proj, out, 1024, 1024);
}

// Round 8
// 149.089 us; speedup vs baseline: 1.0019x; 1.0019x over previous
//
#include <hip/hip_runtime.h>
#include <hip/hip_bf16.h>

// FenwickLogLinearAttention: B=2,T=2048,C=1024,H=16,Dh=64
// R11 = RESUBMIT of R10 (container failed twice = infra flake; kernel audited:
//     no divergent barriers, LDS 112KB legal, VGPR ~320 < 512 @ lb(256,1),
//     staging linearity + swizzle involution verified).
// R10: qkv rebuilt around LDS-READ INTENSITY (closed ledger: R6 qkv = 29.8k
//     MFMA cyc + 67.6k ds_read cyc = 94% of 103.7k total). 4 fat waves of
//     128x96 (tile 256x192, grid 256 = 1/CU, XCD region swizzle): 28 reads vs
//     96 MFMA per wave per K-tile -> MFMA-bound. Stage-early dbuf + 1
//     syncthreads/tile (R8-proj proven). proj/attn/prep unchanged from R8.
// ws layout (bytes): xb@0 (8M) | WqkvT@8M (6M) | QKVb@14M (24M) | AO@38M (8M) | WprojT@46M (2M)

typedef unsigned short ushort_t;
typedef __attribute__((ext_vector_type(8))) short s16x8;
typedef __attribute__((ext_vector_type(4))) float f32x4;

#define T_SEQ 2048
#define C_DIM 1024
#define HEADS 16

__device__ __forceinline__ ushort_t f2bf(float f) {
    union { float f; unsigned u; } v{f};
    unsigned r = v.u + 0x7FFFu + ((v.u >> 16) & 1u);   // RNE
    return (ushort_t)(r >> 16);
}
__device__ __forceinline__ float bf2f(ushort_t u) {
    union { unsigned u; float f; } v{((unsigned)u) << 16};
    return v.f;
}

__device__ __forceinline__ void async16(const ushort_t* g, ushort_t* l) {
    __builtin_amdgcn_global_load_lds(
        (const __attribute__((address_space(1))) void*)g,
        (__attribute__((address_space(3))) void*)l, 16, 0, 0);
}

// ---------------- merged prep: cvt(x)->bf16 + two weight transposes ----------------
__global__ void prep(const float* __restrict__ x, ushort_t* __restrict__ xb,
                     const float* __restrict__ Wq, ushort_t* __restrict__ WqT,
                     const float* __restrict__ Wp, ushort_t* __restrict__ WpT) {
    const int bid = blockIdx.x;
    const int tid = threadIdx.x;
    if (bid < 4096) {
        const int i = bid * 256 + tid;
        float4 f = ((const float4*)x)[i];
        ushort4 o;
        o.x = f2bf(f.x); o.y = f2bf(f.y); o.z = f2bf(f.z); o.w = f2bf(f.w);
        ((ushort4*)xb)[i] = o;
    } else {
        __shared__ ushort_t tile[32][33];
        const float* W; ushort_t* WT; int N, nb, kb;
        if (bid < 7168) {
            const int tb = bid - 4096;
            W = Wq; WT = WqT; N = 3072; nb = (tb % 96) * 32; kb = (tb / 96) * 32;
        } else {
            const int tb = bid - 7168;
            W = Wp; WT = WpT; N = 1024; nb = (tb & 31) * 32; kb = (tb >> 5) * 32;
        }
        const int tx = tid & 31, ty = tid >> 5;
        #pragma unroll
        for (int i = ty; i < 32; i += 8)
            tile[i][tx] = f2bf(W[(size_t)(kb + i) * N + nb + tx]);
        __syncthreads();
        #pragma unroll
        for (int i = ty; i < 32; i += 8)
            WT[(size_t)(nb + i) * 1024 + kb + tx] = tile[tx][i];
    }
}

// ---------------- QKV GEMM: 256x192 tile, 4 fat waves (128x96 each), BK=64 ----------------
// C[M][N] = A[M][K] @ BT[N][K]^T + bias[N], bf16 out.
// LDS: dbuf [2][A 16384 el | B 12288 el] = 112 KiB. Swizzle: slot s of row r
// holds global k-group s ^ (r&7) (linear dest + pre-swizzled source; read XORs).
// Per wave per K-tile: 28 ds_read_b128 (1344 cyc/CU) vs 96 MFMA (1862 cyc/CU).
__global__ __launch_bounds__(256, 1)
void gemm_qkv(const ushort_t* __restrict__ A, const ushort_t* __restrict__ BT,
              const float* __restrict__ bias, ushort_t* __restrict__ C,
              int N, int K) {
    __shared__ ushort_t lds[2][28672];       // 112 KiB

    const int tid  = threadIdx.x;
    const int wave = tid >> 6;
    const int lane = tid & 63;
    const int wm   = wave >> 1;              // 0..1 (M half: 128 rows)
    const int wn   = wave & 1;               // 0..1 (N half: 96 cols)
    const int lrow = lane & 15;
    const int quad = lane >> 4;
    const int d3   = lrow & 7;
    const int crow = lane >> 3;
    const int gcol = (((lane & 7) ^ crow) << 3);   // pre-swizzled global k-group

    // XCD region swizzle: XCD (bid&7) owns a 4-rowblk x 8-colblk region (R6-proven).
    const int bid    = blockIdx.x;
    const int xcd    = bid & 7;
    const int q      = bid >> 3;                    // [0,32)
    const int rowblk = ((xcd & 3) << 2) + (q & 3);  // [0,16)
    const int colblk = ((xcd >> 2) << 3) + (q >> 2);// [0,16)
    const int row0   = rowblk * 256;
    const int col0   = colblk * 192;

    const ushort_t* Ag = A  + (size_t)(row0 + wave * 8 + crow) * K + gcol;
    const ushort_t* Bg = BT + (size_t)(col0 + wave * 8 + crow) * K + gcol;

    f32x4 acc[8][6] = {};

    // stage K-tile t into buffer b: A = 8 calls x 32 rows, B = 6 calls x 32 rows.
    // dest linear: row (u*32 + wave*8 + crow) -> el u*2048 + wave*512 + lane*8.
    #define QSTAGE(t, b) do {                                                      \
        _Pragma("unroll") for (int u = 0; u < 8; ++u)                              \
            async16(Ag + (size_t)(u) * 32 * K + (size_t)(t) * 64,                  \
                    &lds[b][u * 2048 + wave * 512]);                               \
        _Pragma("unroll") for (int u = 0; u < 6; ++u)                              \
            async16(Bg + (size_t)(u) * 32 * K + (size_t)(t) * 64,                  \
                    &lds[b][16384 + u * 2048 + wave * 512]);                       \
    } while (0)

    const int nt = K >> 6;                   // 16 K-tiles
    int cur = 0;
    QSTAGE(0, 0);
    __syncthreads();                          // implicit vmcnt(0): tile0 visible

    for (int t = 0; t < nt; ++t) {
        if (t + 1 < nt) QSTAGE(t + 1, cur ^ 1);   // issued early, lands under MFMA
        s16x8 af[8][2], bfr[6][2];
        #pragma unroll
        for (int i = 0; i < 8; ++i)
            #pragma unroll
            for (int kh = 0; kh < 2; ++kh)
                af[i][kh] = *(const s16x8*)(&lds[cur][
                    ((wm << 7) + i * 16 + lrow) * 64 + (((kh * 4 + quad) ^ d3) << 3)]);
        #pragma unroll
        for (int j = 0; j < 6; ++j)
            #pragma unroll
            for (int kh = 0; kh < 2; ++kh)
                bfr[j][kh] = *(const s16x8*)(&lds[cur][16384 +
                    (wn * 96 + j * 16 + lrow) * 64 + (((kh * 4 + quad) ^ d3) << 3)]);
        #pragma unroll
        for (int i = 0; i < 8; ++i)
            #pragma unroll
            for (int j = 0; j < 6; ++j)
                #pragma unroll
                for (int kh = 0; kh < 2; ++kh)
                    acc[i][j] = __builtin_amdgcn_mfma_f32_16x16x32_bf16(
                        af[i][kh], bfr[j][kh], acc[i][j], 0, 0, 0);
        __syncthreads();                      // one barrier per K-tile
        cur ^= 1;
    }

    // D mapping: col=lane&15, row=quad*4+reg (m89-verified)
    #pragma unroll
    for (int i = 0; i < 8; ++i) {
        #pragma unroll
        for (int j = 0; j < 6; ++j) {
            const int col = col0 + wn * 96 + j * 16 + lrow;
            const float bv = bias[col];
            #pragma unroll
            for (int r = 0; r < 4; ++r) {
                const int row = row0 + (wm << 7) + i * 16 + quad * 4 + r;
                C[(size_t)row * N + col] = f2bf(acc[i][j][r] + bv);
            }
        }
    }
    #undef QSTAGE
}

// ---------------- proj GEMM: 128x128 tile, BK=64, DOUBLE-buffered, 1 sync/tile ----------------
#define PSTAGE(t, b) do {                                                        \
    _Pragma("unroll") for (int it = 0; it < 4; ++it) {                           \
        const int chunk = it * 4 + wave;                                         \
        const int r = chunk * 8 + crow;                                          \
        async16(A  + (size_t)(row0 + r) * K + ((t) * 64 + gcol), lsA[b] + chunk * 512); \
        async16(BT + (size_t)(col0 + r) * K + ((t) * 64 + gcol), lsB[b] + chunk * 512); \
    }                                                                            \
} while (0)

__global__ void gemm_proj(const ushort_t* __restrict__ A, const ushort_t* __restrict__ BT,
                          const float* __restrict__ bias, float* __restrict__ C,
                          int N, int K) {
    __shared__ ushort_t lsA[2][128 * 64];
    __shared__ ushort_t lsB[2][128 * 64];

    const int tid  = threadIdx.x;
    const int wave = tid >> 6;
    const int lane = tid & 63;

    const int bid  = blockIdx.x;
    const int xcd  = bid & 7;
    const int q    = bid >> 3;                 // [0,32)
    const int row0 = (xcd * 4 + (q & 3)) * 128;   // rowblk [0,32)
    const int col0 = (q >> 2) * 128;              // colblk [0,8)

    const int wr   = (wave >> 1) * 64;
    const int wc   = (wave & 1) * 64;
    const int lrow = lane & 15;
    const int quad = lane >> 4;
    const int crow = lane >> 3;
    const int gcol = ((lane & 7) ^ crow) * 8;
    const int d3   = lrow & 7;

    f32x4 acc[4][4] = {};

    const int nt = K >> 6;                     // 16 K-tiles
    int cur = 0;
    PSTAGE(0, 0);
    __syncthreads();                            // drains vmcnt -> tile0 visible
    for (int t = 0; t < nt; ++t) {
        if (t + 1 < nt) PSTAGE(t + 1, cur ^ 1); // overlaps compute below
        #pragma unroll
        for (int kk = 0; kk < 64; kk += 32) {
            const int g = (kk >> 3) + quad;
            const int slot = (g ^ d3) << 3;
            s16x8 af[4], bfr[4];
            #pragma unroll
            for (int i = 0; i < 4; ++i)
                af[i] = *(const s16x8*)(lsA[cur] + (wr + i * 16 + lrow) * 64 + slot);
            #pragma unroll
            for (int j = 0; j < 4; ++j)
                bfr[j] = *(const s16x8*)(lsB[cur] + (wc + j * 16 + lrow) * 64 + slot);
            #pragma unroll
            for (int i = 0; i < 4; ++i)
                #pragma unroll
                for (int j = 0; j < 4; ++j)
                    acc[i][j] = __builtin_amdgcn_mfma_f32_16x16x32_bf16(
                        af[i], bfr[j], acc[i][j], 0, 0, 0);
        }
        __syncthreads();                        // one barrier per tile
        cur ^= 1;
    }

    #pragma unroll
    for (int i = 0; i < 4; ++i) {
        #pragma unroll
        for (int j = 0; j < 4; ++j) {
            const int col = col0 + wc + j * 16 + lrow;
            const float bv = bias[col];
            #pragma unroll
            for (int r = 0; r < 4; ++r) {
                const int row = row0 + wr + i * 16 + quad * 4 + r;
                C[(size_t)row * N + col] = acc[i][j][r] + bv;
            }
        }
    }
}

// ---------------- sparse Fenwick attention ----------------
// bh-per-XCD swizzle: XCD x serves bh in {x, x+8, x+16, x+24} (64 blocks each);
// per-XCD K/V working set = 4 x 512KB = 2MB < 4MB L2.
__global__ void fenwick_attn(const ushort_t* __restrict__ QKV, ushort_t* __restrict__ AO) {
    const int lane = threadIdx.x & 63;
    const int bid  = blockIdx.x;
    const int xcd  = bid & 7;
    const int q    = bid >> 3;                       // [0,256)
    const int bh   = xcd + ((q >> 6) << 3);          // [0,32)
    const int tile = ((q & 63) << 2) + (threadIdx.x >> 6); // [0,256)
    const int h    = bh & (HEADS - 1);
    const int b    = bh >> 4;
    const int tl   = lane >> 3;
    const int g    = lane & 7;
    const int t    = tile * 8 + tl;

    const ushort_t* base = QKV + (size_t)(b * T_SEQ) * 3072 + h * 64 + g * 8;

    float qf[8];
    {
        s16x8 qv = *(const s16x8*)(base + (size_t)t * 3072);
        #pragma unroll
        for (int e = 0; e < 8; ++e) qf[e] = bf2f((ushort_t)qv[e]);
    }

    float logit[12];
    int   pos[12];
    float mx = -1e30f;
    #pragma unroll
    for (int s = 0; s < 12; ++s) {
        const int step = (s == 0) ? 0 : (1 << (s - 1));
        const bool act = (step <= t);
        const int p = act ? (t - step) : t;
        pos[s] = p;
        s16x8 kv = *(const s16x8*)(base + (size_t)p * 3072 + 1024);
        float l = 0.f;
        #pragma unroll
        for (int e = 0; e < 8; ++e) l = fmaf(qf[e], bf2f((ushort_t)kv[e]), l);
        l += __shfl_xor(l, 1, 64);
        l += __shfl_xor(l, 2, 64);
        l += __shfl_xor(l, 4, 64);
        l *= 0.125f;                       // Dh^-0.5
        logit[s] = act ? l : -1e30f;
        mx = fmaxf(mx, logit[s]);
    }

    float denom = 0.f;
    float ov[8] = {};
    #pragma unroll
    for (int s = 0; s < 12; ++s) {
        const float w = __expf(logit[s] - mx);
        denom += w;
        s16x8 vv = *(const s16x8*)(base + (size_t)pos[s] * 3072 + 2048);
        #pragma unroll
        for (int e = 0; e < 8; ++e) ov[e] = fmaf(w, bf2f((ushort_t)vv[e]), ov[e]);
    }

    const float inv = 1.f / denom;
    s16x8 os;
    #pragma unroll
    for (int e = 0; e < 8; ++e) os[e] = (short)f2bf(ov[e] * inv);
    *(s16x8*)(AO + (size_t)(b * T_SEQ + t) * C_DIM + h * 64 + g * 8) = os;
}

extern "C" void kernel_launch(void* const* d_in, const int* in_sizes, int n_in,
                              void* d_out, int out_size, void* d_ws, size_t ws_size,
                              hipStream_t stream) {
    const float* x      = (const float*)d_in[0];
    const float* W_qkv  = (const float*)d_in[1];
    const float* b_qkv  = (const float*)d_in[2];
    const float* W_proj = (const float*)d_in[3];
    const float* b_proj = (const float*)d_in[4];
    float* out = (float*)d_out;

    char* ws = (char*)d_ws;
    ushort_t* xb     = (ushort_t*)(ws);                        // 4096x1024 bf16
    ushort_t* WqkvT  = (ushort_t*)(ws + (size_t)8  * 1048576); // 3072x1024 bf16
    ushort_t* QKVb   = (ushort_t*)(ws + (size_t)14 * 1048576); // 4096x3072 bf16
    ushort_t* AO     = (ushort_t*)(ws + (size_t)38 * 1048576); // 4096x1024 bf16
    ushort_t* WprojT = (ushort_t*)(ws + (size_t)46 * 1048576); // 1024x1024 bf16

    prep<<<8192, 256, 0, stream>>>(x, xb, W_qkv, WqkvT, W_proj, WprojT);
    gemm_qkv<<<256, 256, 0, stream>>>(xb, WqkvT, b_qkv, QKVb, 3072, 1024);
    fenwick_attn<<<2048, 256, 0, stream>>>(QKVb, AO);
    gemm_proj<<<256, 256, 0, stream>>>(AO, WprojT, b_proj, out, 1024, 1024);
}

// Round 9
// 147.054 us; speedup vs baseline: 1.0158x; 1.0138x over previous
//
#include <hip/hip_runtime.h>
#include <hip/hip_bf16.h>

// FenwickLogLinearAttention: B=2,T=2048,C=1024,H=16,Dh=64
// R12: qkv = minimal-LDS-traffic tile WITH cross-block desync (the two proven
//     ingredients never combined): 128x192 tile, 4 waves of 64x96 (traffic
//     coeff 0.026, best at >=2 waves/SIMD), single-buffered 40KB LDS, m97
//     2-barrier loop, grid 512 = 2 blocks/CU (8 waves/CU = 2/SIMD; block A's
//     stage/vmcnt/barrier overlaps block B's MFMA — m114). R11 failed on
//     1 wave/SIMD (no TLP); R4-R8 failed on 1-block lockstep (pipes alternate).
//     VGPR ~210 @ launch_bounds(256,2). XCD region 8x8 blocks (5MB, R6-proven).
//     proj (dbuf 1-sync)/attn/prep unchanged from R8.
// ws layout (bytes): xb@0 (8M) | WqkvT@8M (6M) | QKVb@14M (24M) | AO@38M (8M) | WprojT@46M (2M)

typedef unsigned short ushort_t;
typedef __attribute__((ext_vector_type(8))) short s16x8;
typedef __attribute__((ext_vector_type(4))) float f32x4;

#define T_SEQ 2048
#define C_DIM 1024
#define HEADS 16

__device__ __forceinline__ ushort_t f2bf(float f) {
    union { float f; unsigned u; } v{f};
    unsigned r = v.u + 0x7FFFu + ((v.u >> 16) & 1u);   // RNE
    return (ushort_t)(r >> 16);
}
__device__ __forceinline__ float bf2f(ushort_t u) {
    union { unsigned u; float f; } v{((unsigned)u) << 16};
    return v.f;
}

__device__ __forceinline__ void async16(const ushort_t* g, ushort_t* l) {
    __builtin_amdgcn_global_load_lds(
        (const __attribute__((address_space(1))) void*)g,
        (__attribute__((address_space(3))) void*)l, 16, 0, 0);
}

// ---------------- merged prep: cvt(x)->bf16 + two weight transposes ----------------
__global__ void prep(const float* __restrict__ x, ushort_t* __restrict__ xb,
                     const float* __restrict__ Wq, ushort_t* __restrict__ WqT,
                     const float* __restrict__ Wp, ushort_t* __restrict__ WpT) {
    const int bid = blockIdx.x;
    const int tid = threadIdx.x;
    if (bid < 4096) {
        const int i = bid * 256 + tid;
        float4 f = ((const float4*)x)[i];
        ushort4 o;
        o.x = f2bf(f.x); o.y = f2bf(f.y); o.z = f2bf(f.z); o.w = f2bf(f.w);
        ((ushort4*)xb)[i] = o;
    } else {
        __shared__ ushort_t tile[32][33];
        const float* W; ushort_t* WT; int N, nb, kb;
        if (bid < 7168) {
            const int tb = bid - 4096;
            W = Wq; WT = WqT; N = 3072; nb = (tb % 96) * 32; kb = (tb / 96) * 32;
        } else {
            const int tb = bid - 7168;
            W = Wp; WT = WpT; N = 1024; nb = (tb & 31) * 32; kb = (tb >> 5) * 32;
        }
        const int tx = tid & 31, ty = tid >> 5;
        #pragma unroll
        for (int i = ty; i < 32; i += 8)
            tile[i][tx] = f2bf(W[(size_t)(kb + i) * N + nb + tx]);
        __syncthreads();
        #pragma unroll
        for (int i = ty; i < 32; i += 8)
            WT[(size_t)(nb + i) * 1024 + kb + tx] = tile[tx][i];
    }
}

// ---------------- QKV GEMM: 128x192 tile, 4 waves of 64x96, BK=64, 2 blocks/CU ----------------
// C[M][N] = A[M][K] @ BT[N][K]^T + bias[N], bf16 out.
// LDS single buffer 40KB: A 128x64 (8192 el) | B 192x64 (12288 el).
// Swizzle: slot s of row r holds k-group s ^ (r&7) (pre-swizzled source, read XORs).
// Per wave per K-tile: 20 ds_read_b128; per block 80 (960 cyc) + 320 stage-write
// vs MFMA 192 (932 cyc/SIMD-pair) — balanced; 2 desynced blocks/CU overlap stalls.
__global__ __launch_bounds__(256, 2)
void gemm_qkv(const ushort_t* __restrict__ A, const ushort_t* __restrict__ BT,
              const float* __restrict__ bias, ushort_t* __restrict__ C,
              int N, int K) {
    __shared__ ushort_t lds[20480];          // 40 KiB

    const int tid  = threadIdx.x;
    const int wave = tid >> 6;
    const int lane = tid & 63;
    const int wm   = wave >> 1;              // 0..1 (M half: 64 rows)
    const int wn   = wave & 1;               // 0..1 (N half: 96 cols)
    const int lrow = lane & 15;
    const int quad = lane >> 4;
    const int d3   = lrow & 7;
    const int crow = lane >> 3;
    const int gcol = (((lane & 7) ^ crow) << 3);   // pre-swizzled global k-group

    // XCD region swizzle: XCD (bid&7) owns 8 rowblk x 8 colblk (A 2MB + B 3MB).
    const int bid    = blockIdx.x;
    const int xcd    = bid & 7;
    const int q      = bid >> 3;                    // [0,64)
    const int rowblk = ((xcd & 3) << 3) + (q & 7);  // [0,32)
    const int colblk = ((xcd >> 2) << 3) + (q >> 3);// [0,16)
    const int row0   = rowblk * 128;
    const int col0   = colblk * 192;

    const ushort_t* Ag = A  + (size_t)(row0 + wave * 8 + crow) * K + gcol;
    const ushort_t* Bg = BT + (size_t)(col0 + wave * 8 + crow) * K + gcol;

    f32x4 acc[4][6] = {};

    // stage K-tile t: A 4 calls x 32 rows (128), B 6 calls x 32 rows (192).
    // dest linear: A el u*2048 + wave*512 + lane*8; B base 8192.
    #define QSTAGE(t) do {                                                         \
        _Pragma("unroll") for (int u = 0; u < 4; ++u)                              \
            async16(Ag + (size_t)(u) * 32 * K + (size_t)(t) * 64,                  \
                    &lds[u * 2048 + wave * 512]);                                  \
        _Pragma("unroll") for (int u = 0; u < 6; ++u)                              \
            async16(Bg + (size_t)(u) * 32 * K + (size_t)(t) * 64,                  \
                    &lds[8192 + u * 2048 + wave * 512]);                           \
    } while (0)

    const int nt = K >> 6;                   // 16 K-tiles
    for (int t = 0; t < nt; ++t) {
        QSTAGE(t);
        __syncthreads();                      // implicit vmcnt(0): tile visible
        s16x8 af[4][2], bfr[6][2];
        #pragma unroll
        for (int i = 0; i < 4; ++i)
            #pragma unroll
            for (int kh = 0; kh < 2; ++kh)
                af[i][kh] = *(const s16x8*)(&lds[
                    (wm * 64 + i * 16 + lrow) * 64 + (((kh * 4 + quad) ^ d3) << 3)]);
        #pragma unroll
        for (int j = 0; j < 6; ++j)
            #pragma unroll
            for (int kh = 0; kh < 2; ++kh)
                bfr[j][kh] = *(const s16x8*)(&lds[8192 +
                    (wn * 96 + j * 16 + lrow) * 64 + (((kh * 4 + quad) ^ d3) << 3)]);
        #pragma unroll
        for (int i = 0; i < 4; ++i)
            #pragma unroll
            for (int j = 0; j < 6; ++j)
                #pragma unroll
                for (int kh = 0; kh < 2; ++kh)
                    acc[i][j] = __builtin_amdgcn_mfma_f32_16x16x32_bf16(
                        af[i][kh], bfr[j][kh], acc[i][j], 0, 0, 0);
        __syncthreads();                      // all reads done before next stage
    }

    // D mapping: col=lane&15, row=quad*4+reg (m89-verified)
    #pragma unroll
    for (int i = 0; i < 4; ++i) {
        #pragma unroll
        for (int j = 0; j < 6; ++j) {
            const int col = col0 + wn * 96 + j * 16 + lrow;
            const float bv = bias[col];
            #pragma unroll
            for (int r = 0; r < 4; ++r) {
                const int row = row0 + wm * 64 + i * 16 + quad * 4 + r;
                C[(size_t)row * N + col] = f2bf(acc[i][j][r] + bv);
            }
        }
    }
    #undef QSTAGE
}

// ---------------- proj GEMM: 128x128 tile, BK=64, DOUBLE-buffered, 1 sync/tile ----------------
#define PSTAGE(t, b) do {                                                        \
    _Pragma("unroll") for (int it = 0; it < 4; ++it) {                           \
        const int chunk = it * 4 + wave;                                         \
        const int r = chunk * 8 + crow;                                          \
        async16(A  + (size_t)(row0 + r) * K + ((t) * 64 + gcol), lsA[b] + chunk * 512); \
        async16(BT + (size_t)(col0 + r) * K + ((t) * 64 + gcol), lsB[b] + chunk * 512); \
    }                                                                            \
} while (0)

__global__ void gemm_proj(const ushort_t* __restrict__ A, const ushort_t* __restrict__ BT,
                          const float* __restrict__ bias, float* __restrict__ C,
                          int N, int K) {
    __shared__ ushort_t lsA[2][128 * 64];
    __shared__ ushort_t lsB[2][128 * 64];

    const int tid  = threadIdx.x;
    const int wave = tid >> 6;
    const int lane = tid & 63;

    const int bid  = blockIdx.x;
    const int xcd  = bid & 7;
    const int q    = bid >> 3;                 // [0,32)
    const int row0 = (xcd * 4 + (q & 3)) * 128;   // rowblk [0,32)
    const int col0 = (q >> 2) * 128;              // colblk [0,8)

    const int wr   = (wave >> 1) * 64;
    const int wc   = (wave & 1) * 64;
    const int lrow = lane & 15;
    const int quad = lane >> 4;
    const int crow = lane >> 3;
    const int gcol = ((lane & 7) ^ crow) * 8;
    const int d3   = lrow & 7;

    f32x4 acc[4][4] = {};

    const int nt = K >> 6;                     // 16 K-tiles
    int cur = 0;
    PSTAGE(0, 0);
    __syncthreads();                            // drains vmcnt -> tile0 visible
    for (int t = 0; t < nt; ++t) {
        if (t + 1 < nt) PSTAGE(t + 1, cur ^ 1); // overlaps compute below
        #pragma unroll
        for (int kk = 0; kk < 64; kk += 32) {
            const int g = (kk >> 3) + quad;
            const int slot = (g ^ d3) << 3;
            s16x8 af[4], bfr[4];
            #pragma unroll
            for (int i = 0; i < 4; ++i)
                af[i] = *(const s16x8*)(lsA[cur] + (wr + i * 16 + lrow) * 64 + slot);
            #pragma unroll
            for (int j = 0; j < 4; ++j)
                bfr[j] = *(const s16x8*)(lsB[cur] + (wc + j * 16 + lrow) * 64 + slot);
            #pragma unroll
            for (int i = 0; i < 4; ++i)
                #pragma unroll
                for (int j = 0; j < 4; ++j)
                    acc[i][j] = __builtin_amdgcn_mfma_f32_16x16x32_bf16(
                        af[i], bfr[j], acc[i][j], 0, 0, 0);
        }
        __syncthreads();                        // one barrier per tile
        cur ^= 1;
    }

    #pragma unroll
    for (int i = 0; i < 4; ++i) {
        #pragma unroll
        for (int j = 0; j < 4; ++j) {
            const int col = col0 + wc + j * 16 + lrow;
            const float bv = bias[col];
            #pragma unroll
            for (int r = 0; r < 4; ++r) {
                const int row = row0 + wr + i * 16 + quad * 4 + r;
                C[(size_t)row * N + col] = acc[i][j][r] + bv;
            }
        }
    }
}

// ---------------- sparse Fenwick attention ----------------
// bh-per-XCD swizzle: XCD x serves bh in {x, x+8, x+16, x+24} (64 blocks each);
// per-XCD K/V working set = 4 x 512KB = 2MB < 4MB L2.
__global__ void fenwick_attn(const ushort_t* __restrict__ QKV, ushort_t* __restrict__ AO) {
    const int lane = threadIdx.x & 63;
    const int bid  = blockIdx.x;
    const int xcd  = bid & 7;
    const int q    = bid >> 3;                       // [0,256)
    const int bh   = xcd + ((q >> 6) << 3);          // [0,32)
    const int tile = ((q & 63) << 2) + (threadIdx.x >> 6); // [0,256)
    const int h    = bh & (HEADS - 1);
    const int b    = bh >> 4;
    const int tl   = lane >> 3;
    const int g    = lane & 7;
    const int t    = tile * 8 + tl;

    const ushort_t* base = QKV + (size_t)(b * T_SEQ) * 3072 + h * 64 + g * 8;

    float qf[8];
    {
        s16x8 qv = *(const s16x8*)(base + (size_t)t * 3072);
        #pragma unroll
        for (int e = 0; e < 8; ++e) qf[e] = bf2f((ushort_t)qv[e]);
    }

    float logit[12];
    int   pos[12];
    float mx = -1e30f;
    #pragma unroll
    for (int s = 0; s < 12; ++s) {
        const int step = (s == 0) ? 0 : (1 << (s - 1));
        const bool act = (step <= t);
        const int p = act ? (t - step) : t;
        pos[s] = p;
        s16x8 kv = *(const s16x8*)(base + (size_t)p * 3072 + 1024);
        float l = 0.f;
        #pragma unroll
        for (int e = 0; e < 8; ++e) l = fmaf(qf[e], bf2f((ushort_t)kv[e]), l);
        l += __shfl_xor(l, 1, 64);
        l += __shfl_xor(l, 2, 64);
        l += __shfl_xor(l, 4, 64);
        l *= 0.125f;                       // Dh^-0.5
        logit[s] = act ? l : -1e30f;
        mx = fmaxf(mx, logit[s]);
    }

    float denom = 0.f;
    float ov[8] = {};
    #pragma unroll
    for (int s = 0; s < 12; ++s) {
        const float w = __expf(logit[s] - mx);
        denom += w;
        s16x8 vv = *(const s16x8*)(base + (size_t)pos[s] * 3072 + 2048);
        #pragma unroll
        for (int e = 0; e < 8; ++e) ov[e] = fmaf(w, bf2f((ushort_t)vv[e]), ov[e]);
    }

    const float inv = 1.f / denom;
    s16x8 os;
    #pragma unroll
    for (int e = 0; e < 8; ++e) os[e] = (short)f2bf(ov[e] * inv);
    *(s16x8*)(AO + (size_t)(b * T_SEQ + t) * C_DIM + h * 64 + g * 8) = os;
}

extern "C" void kernel_launch(void* const* d_in, const int* in_sizes, int n_in,
                              void* d_out, int out_size, void* d_ws, size_t ws_size,
                              hipStream_t stream) {
    const float* x      = (const float*)d_in[0];
    const float* W_qkv  = (const float*)d_in[1];
    const float* b_qkv  = (const float*)d_in[2];
    const float* W_proj = (const float*)d_in[3];
    const float* b_proj = (const float*)d_in[4];
    float* out = (float*)d_out;

    char* ws = (char*)d_ws;
    ushort_t* xb     = (ushort_t*)(ws);                        // 4096x1024 bf16
    ushort_t* WqkvT  = (ushort_t*)(ws + (size_t)8  * 1048576); // 3072x1024 bf16
    ushort_t* QKVb   = (ushort_t*)(ws + (size_t)14 * 1048576); // 4096x3072 bf16
    ushort_t* AO     = (ushort_t*)(ws + (size_t)38 * 1048576); // 4096x1024 bf16
    ushort_t* WprojT = (ushort_t*)(ws + (size_t)46 * 1048576); // 1024x1024 bf16

    prep<<<8192, 256, 0, stream>>>(x, xb, W_qkv, WqkvT, W_proj, WprojT);
    gemm_qkv<<<512, 256, 0, stream>>>(xb, WqkvT, b_qkv, QKVb, 3072, 1024);
    fenwick_attn<<<2048, 256, 0, stream>>>(QKVb, AO);
    gemm_proj<<<256, 256, 0, stream>>>(AO, WprojT, b_proj, out, 1024, 1024);
}

// Round 10
// 144.439 us; speedup vs baseline: 1.0341x; 1.0181x over previous
//
#include <hip/hip_runtime.h>
#include <hip/hip_bf16.h>

// FenwickLogLinearAttention: B=2,T=2048,C=1024,H=16,Dh=64
// R13 = RESTORE R8 (best measured: 145.5us). Rounds 9-12 perturbed qkv away
//     from this config and all regressed (147.1-149.4). Nine qkv structures
//     (2-bar, 8-phase, 4-phase, 1-bar, 1/2/3 blocks/CU, thin/fat waves) all
//     land 42+-2us -> plateau is schedule/occupancy-invariant at K=1024;
//     remaining gap vs floor is prologue/epilogue amortization (16 K-iters)
//     + staging-drain serialization, not addressable at this structure family.
//     Fixed harness cost (timed 268MB poison fills) = 78.4us of the total.
// qkv: 256x192 tile, 4-phase single-barrier counted-vmcnt, XCD 4x8 regions.
// proj: 128x128 dbuf, stage-early, 1 sync/tile, XCD regions.
// attn: bh-per-XCD swizzle (2MB K/V per XCD L2). prep: merged cvt+transposes.
// ws layout (bytes): xb@0 (8M) | WqkvT@8M (6M) | QKVb@14M (24M) | AO@38M (8M) | WprojT@46M (2M)

typedef unsigned short ushort_t;
typedef __attribute__((ext_vector_type(8))) short s16x8;
typedef __attribute__((ext_vector_type(4))) float f32x4;

#define T_SEQ 2048
#define C_DIM 1024
#define HEADS 16

__device__ __forceinline__ ushort_t f2bf(float f) {
    union { float f; unsigned u; } v{f};
    unsigned r = v.u + 0x7FFFu + ((v.u >> 16) & 1u);   // RNE
    return (ushort_t)(r >> 16);
}
__device__ __forceinline__ float bf2f(ushort_t u) {
    union { unsigned u; float f; } v{((unsigned)u) << 16};
    return v.f;
}

__device__ __forceinline__ void async16(const ushort_t* g, ushort_t* l) {
    __builtin_amdgcn_global_load_lds(
        (const __attribute__((address_space(1))) void*)g,
        (__attribute__((address_space(3))) void*)l, 16, 0, 0);
}

// ---------------- merged prep: cvt(x)->bf16 + two weight transposes ----------------
__global__ void prep(const float* __restrict__ x, ushort_t* __restrict__ xb,
                     const float* __restrict__ Wq, ushort_t* __restrict__ WqT,
                     const float* __restrict__ Wp, ushort_t* __restrict__ WpT) {
    const int bid = blockIdx.x;
    const int tid = threadIdx.x;
    if (bid < 4096) {
        const int i = bid * 256 + tid;
        float4 f = ((const float4*)x)[i];
        ushort4 o;
        o.x = f2bf(f.x); o.y = f2bf(f.y); o.z = f2bf(f.z); o.w = f2bf(f.w);
        ((ushort4*)xb)[i] = o;
    } else {
        __shared__ ushort_t tile[32][33];
        const float* W; ushort_t* WT; int N, nb, kb;
        if (bid < 7168) {
            const int tb = bid - 4096;
            W = Wq; WT = WqT; N = 3072; nb = (tb % 96) * 32; kb = (tb / 96) * 32;
        } else {
            const int tb = bid - 7168;
            W = Wp; WT = WpT; N = 1024; nb = (tb & 31) * 32; kb = (tb >> 5) * 32;
        }
        const int tx = tid & 31, ty = tid >> 5;
        #pragma unroll
        for (int i = ty; i < 32; i += 8)
            tile[i][tx] = f2bf(W[(size_t)(kb + i) * N + nb + tx]);
        __syncthreads();
        #pragma unroll
        for (int i = ty; i < 32; i += 8)
            WT[(size_t)(nb + i) * 1024 + kb + tx] = tile[tx][i];
    }
}

// ---------------- QKV GEMM: 256x192 tile, BK=64, 4-phase single-barrier ----------------
#define WAIT_LGKM0() do { asm volatile("s_waitcnt lgkmcnt(0)" ::: "memory"); \
                          __builtin_amdgcn_sched_barrier(0); } while (0)
#define WAIT_VM(n)  asm volatile("s_waitcnt vmcnt(" #n ")" ::: "memory")

#define SA(kt, u, dst) async16(Ag + (size_t)(u) * rstep + (size_t)(kt) * 64, \
                               (dst) + (u) * 4096 + wave * 512)
#define SB(kt, u, dst) async16(Bg + (size_t)(u) * rstep + (size_t)(kt) * 64, \
                               (dst) + (u) * 4096 + wave * 512)

#define LDA_FRAG(buf, i, kh) (*(const s16x8*)((buf) + ((wm << 7) + (i) * 16 + lrow) * 64 \
                               + ((((kh) * 4 + quad) ^ d3) << 3)))
#define LDB_FRAG(buf, j, kh) (*(const s16x8*)((buf) + (wn * 48 + (j) * 16 + lrow) * 64 \
                               + ((((kh) * 4 + quad) ^ d3) << 3)))

// one phase: reads; stages; (collective-to-be vmcnt); BARRIER; lgkm; 24 MFMA.
// No trailing barrier: waves skew into the next phase's read region while
// others finish MFMA -> LDS pipe and MFMA pipe overlap.
#define PHASE3(lAb, lBb, F0, LOADB, STAGES, PREBAR)                             \
  {                                                                             \
    s16x8 af[4][2];                                                             \
    _Pragma("unroll") for (int ii = 0; ii < 4; ++ii)                            \
      _Pragma("unroll") for (int kh = 0; kh < 2; ++kh)                          \
        af[ii][kh] = LDA_FRAG(lAb, (F0) + ii, kh);                              \
    if (LOADB) {                                                                \
      _Pragma("unroll") for (int j = 0; j < 3; ++j)                             \
        _Pragma("unroll") for (int kh = 0; kh < 2; ++kh)                        \
          bf[j][kh] = LDB_FRAG(lBb, j, kh);                                     \
    }                                                                           \
    STAGES;                                                                     \
    PREBAR;                                                                     \
    __builtin_amdgcn_s_barrier();                                               \
    WAIT_LGKM0();                                                               \
    __builtin_amdgcn_s_setprio(1);                                              \
    _Pragma("unroll") for (int ii = 0; ii < 4; ++ii)                            \
      _Pragma("unroll") for (int j = 0; j < 3; ++j)                             \
        _Pragma("unroll") for (int kh = 0; kh < 2; ++kh)                        \
          acc[(F0) + ii][j] = __builtin_amdgcn_mfma_f32_16x16x32_bf16(          \
              af[ii][kh], bf[j][kh], acc[(F0) + ii][j], 0, 0, 0);               \
    __builtin_amdgcn_s_setprio(0);                                              \
  }

__global__ __launch_bounds__(512, 2)
void gemm_qkv(const ushort_t* __restrict__ A, const ushort_t* __restrict__ BT,
              const float* __restrict__ bias, ushort_t* __restrict__ C,
              int N, int K) {
    __shared__ ushort_t lds[57344];          // 112 KiB

    const int tid  = threadIdx.x;
    const int wave = tid >> 6;
    const int lane = tid & 63;
    const int wm   = wave >> 2;              // 0..1  (M half)
    const int wn   = wave & 3;               // 0..3  (N quarter: 48 cols)
    const int lrow = lane & 15;
    const int quad = lane >> 4;
    const int d3   = lrow & 7;
    const int crow = lane >> 3;
    const int gcol = (((lane & 7) ^ crow) << 3);   // pre-swizzled global k-group

    // XCD region swizzle: XCD (bid&7) owns a 4-rowblk x 8-colblk region.
    const int bid    = blockIdx.x;
    const int xcd    = bid & 7;
    const int q      = bid >> 3;                   // [0,32)
    const int rowblk = ((xcd & 3) << 2) + (q & 3); // [0,16)
    const int colblk = ((xcd >> 2) << 3) + (q >> 2);// [0,16)
    const int row0   = rowblk * 256;
    const int col0   = colblk * 192;

    ushort_t* const lA0 = lds;                       // A buf0: 16384 el
    ushort_t* const lB0 = lds + 16384;               // B buf0: 12288 el
    ushort_t* const lA1 = lds + 28672;               // A buf1
    ushort_t* const lB1 = lds + 45056;               // B buf1

    const ushort_t* Ag = A  + (size_t)(row0 + wave * 8 + crow) * K + gcol;
    const ushort_t* Bg = BT + (size_t)(col0 + wave * 8 + crow) * K + gcol;
    const size_t rstep = (size_t)64 * K;             // 64-row stage unit

    f32x4 acc[8][3] = {};
    s16x8 bf[3][2];

    // prologue: tile0 fully (7 loads), then tile1 partial (5, steady-P4 order)
    SA(0, 0, lA0); SA(0, 1, lA0); SA(0, 2, lA0); SA(0, 3, lA0);
    SB(0, 0, lB0); SB(0, 1, lB0); SB(0, 2, lB0);
    SB(1, 0, lB1); SB(1, 1, lB1); SB(1, 2, lB1); SA(1, 0, lA1); SA(1, 2, lA1);
    WAIT_VM(5);
    __builtin_amdgcn_s_barrier();

    // vmcnt ledger (per wave, steady state): enter P1 with 5 outstanding
    // (tile t+1 partial {B0,B1,B2,A0,A2}); P1 +2 (t+1 A1,A3) = 7;
    // P2 +5 (t+2 partial) = 12, vmcnt(5) pre-BAR -> tile t+1 fully landed,
    // collectivized by BAR_P2, read in P3/P4. Mirror for P3/P4 -> tile t+2.
    const int nt = K >> 6;                           // 16 K-tiles
    for (int t = 0; t < nt; t += 2) {
        const bool s2 = (t + 2) < nt;
        // P1: buf0 frags 0-3 (+bf); stage A(t+1) u1,u3 -> lA1
        PHASE3(lA0, lB0, 0, true, { SA(t + 1, 1, lA1); SA(t + 1, 3, lA1); }, {});
        // P2: buf0 frags 4-7; stage t+2 partial -> lB0, lA0 u0,u2 (read in P1);
        //     vmcnt(5) pre-BAR: tile t+1 landed (tail: drain all for tile t+1)
        PHASE3(lA0, lB0, 4, false,
               { if (s2) { SB(t + 2, 0, lB0); SB(t + 2, 1, lB0); SB(t + 2, 2, lB0);
                           SA(t + 2, 0, lA0); SA(t + 2, 2, lA0); } },
               { if (s2) { WAIT_VM(5); } else { WAIT_VM(0); } });
        // P3: buf1 frags 0-3 (+bf); stage A(t+2) u1,u3 -> lA0 (read in P2)
        PHASE3(lA1, lB1, 0, true, { if (s2) { SA(t + 2, 1, lA0); SA(t + 2, 3, lA0); } }, {});
        // P4: buf1 frags 4-7; stage t+3 partial -> lB1, lA1 u0,u2 (read in P3);
        //     vmcnt(5) pre-BAR: tile t+2 landed
        PHASE3(lA1, lB1, 4, false,
               { if (s2) { SB(t + 3, 0, lB1); SB(t + 3, 1, lB1); SB(t + 3, 2, lB1);
                           SA(t + 3, 0, lA1); SA(t + 3, 2, lA1); } },
               { if (s2) { WAIT_VM(5); } });
    }

    // D mapping: col=lane&15, row=quad*4+reg (m89-verified)
    #pragma unroll
    for (int i = 0; i < 8; ++i) {
        #pragma unroll
        for (int j = 0; j < 3; ++j) {
            const int col = col0 + wn * 48 + j * 16 + lrow;
            const float bv = bias[col];
            #pragma unroll
            for (int r = 0; r < 4; ++r) {
                const int row = row0 + (wm << 7) + i * 16 + quad * 4 + r;
                C[(size_t)row * N + col] = f2bf(acc[i][j][r] + bv);
            }
        }
    }
}

// ---------------- proj GEMM: 128x128 tile, BK=64, DOUBLE-buffered, 1 sync/tile ----------------
// Stage t+1 issued BEFORE compute(t); __syncthreads (implicit vmcnt0+lgkm0
// drain, collective) once per tile. XCD region swizzle as R6.
#define PSTAGE(t, b) do {                                                        \
    _Pragma("unroll") for (int it = 0; it < 4; ++it) {                           \
        const int chunk = it * 4 + wave;                                         \
        const int r = chunk * 8 + crow;                                          \
        async16(A  + (size_t)(row0 + r) * K + ((t) * 64 + gcol), lsA[b] + chunk * 512); \
        async16(BT + (size_t)(col0 + r) * K + ((t) * 64 + gcol), lsB[b] + chunk * 512); \
    }                                                                            \
} while (0)

__global__ void gemm_proj(const ushort_t* __restrict__ A, const ushort_t* __restrict__ BT,
                          const float* __restrict__ bias, float* __restrict__ C,
                          int N, int K) {
    __shared__ ushort_t lsA[2][128 * 64];
    __shared__ ushort_t lsB[2][128 * 64];

    const int tid  = threadIdx.x;
    const int wave = tid >> 6;
    const int lane = tid & 63;

    const int bid  = blockIdx.x;
    const int xcd  = bid & 7;
    const int q    = bid >> 3;                 // [0,32)
    const int row0 = (xcd * 4 + (q & 3)) * 128;   // rowblk [0,32)
    const int col0 = (q >> 2) * 128;              // colblk [0,8)

    const int wr   = (wave >> 1) * 64;
    const int wc   = (wave & 1) * 64;
    const int lrow = lane & 15;
    const int quad = lane >> 4;
    const int crow = lane >> 3;
    const int gcol = ((lane & 7) ^ crow) * 8;
    const int d3   = lrow & 7;

    f32x4 acc[4][4] = {};

    const int nt = K >> 6;                     // 16 K-tiles
    int cur = 0;
    PSTAGE(0, 0);
    __syncthreads();                            // drains vmcnt -> tile0 visible
    for (int t = 0; t < nt; ++t) {
        if (t + 1 < nt) PSTAGE(t + 1, cur ^ 1); // overlaps compute below
        #pragma unroll
        for (int kk = 0; kk < 64; kk += 32) {
            const int g = (kk >> 3) + quad;
            const int slot = (g ^ d3) << 3;
            s16x8 af[4], bfr[4];
            #pragma unroll
            for (int i = 0; i < 4; ++i)
                af[i] = *(const s16x8*)(lsA[cur] + (wr + i * 16 + lrow) * 64 + slot);
            #pragma unroll
            for (int j = 0; j < 4; ++j)
                bfr[j] = *(const s16x8*)(lsB[cur] + (wc + j * 16 + lrow) * 64 + slot);
            #pragma unroll
            for (int i = 0; i < 4; ++i)
                #pragma unroll
                for (int j = 0; j < 4; ++j)
                    acc[i][j] = __builtin_amdgcn_mfma_f32_16x16x32_bf16(
                        af[i], bfr[j], acc[i][j], 0, 0, 0);
        }
        __syncthreads();                        // one barrier per tile
        cur ^= 1;
    }

    #pragma unroll
    for (int i = 0; i < 4; ++i) {
        #pragma unroll
        for (int j = 0; j < 4; ++j) {
            const int col = col0 + wc + j * 16 + lrow;
            const float bv = bias[col];
            #pragma unroll
            for (int r = 0; r < 4; ++r) {
                const int row = row0 + wr + i * 16 + quad * 4 + r;
                C[(size_t)row * N + col] = acc[i][j][r] + bv;
            }
        }
    }
}

// ---------------- sparse Fenwick attention ----------------
// bh-per-XCD swizzle: XCD x serves bh in {x, x+8, x+16, x+24} (64 blocks each);
// per-XCD K/V working set = 4 x 512KB = 2MB < 4MB L2.
__global__ void fenwick_attn(const ushort_t* __restrict__ QKV, ushort_t* __restrict__ AO) {
    const int lane = threadIdx.x & 63;
    const int bid  = blockIdx.x;
    const int xcd  = bid & 7;
    const int q    = bid >> 3;                       // [0,256)
    const int bh   = xcd + ((q >> 6) << 3);          // [0,32)
    const int tile = ((q & 63) << 2) + (threadIdx.x >> 6); // [0,256)
    const int h    = bh & (HEADS - 1);
    const int b    = bh >> 4;
    const int tl   = lane >> 3;
    const int g    = lane & 7;
    const int t    = tile * 8 + tl;

    const ushort_t* base = QKV + (size_t)(b * T_SEQ) * 3072 + h * 64 + g * 8;

    float qf[8];
    {
        s16x8 qv = *(const s16x8*)(base + (size_t)t * 3072);
        #pragma unroll
        for (int e = 0; e < 8; ++e) qf[e] = bf2f((ushort_t)qv[e]);
    }

    float logit[12];
    int   pos[12];
    float mx = -1e30f;
    #pragma unroll
    for (int s = 0; s < 12; ++s) {
        const int step = (s == 0) ? 0 : (1 << (s - 1));
        const bool act = (step <= t);
        const int p = act ? (t - step) : t;
        pos[s] = p;
        s16x8 kv = *(const s16x8*)(base + (size_t)p * 3072 + 1024);
        float l = 0.f;
        #pragma unroll
        for (int e = 0; e < 8; ++e) l = fmaf(qf[e], bf2f((ushort_t)kv[e]), l);
        l += __shfl_xor(l, 1, 64);
        l += __shfl_xor(l, 2, 64);
        l += __shfl_xor(l, 4, 64);
        l *= 0.125f;                       // Dh^-0.5
        logit[s] = act ? l : -1e30f;
        mx = fmaxf(mx, logit[s]);
    }

    float denom = 0.f;
    float ov[8] = {};
    #pragma unroll
    for (int s = 0; s < 12; ++s) {
        const float w = __expf(logit[s] - mx);
        denom += w;
        s16x8 vv = *(const s16x8*)(base + (size_t)pos[s] * 3072 + 2048);
        #pragma unroll
        for (int e = 0; e < 8; ++e) ov[e] = fmaf(w, bf2f((ushort_t)vv[e]), ov[e]);
    }

    const float inv = 1.f / denom;
    s16x8 os;
    #pragma unroll
    for (int e = 0; e < 8; ++e) os[e] = (short)f2bf(ov[e] * inv);
    *(s16x8*)(AO + (size_t)(b * T_SEQ + t) * C_DIM + h * 64 + g * 8) = os;
}

extern "C" void kernel_launch(void* const* d_in, const int* in_sizes, int n_in,
                              void* d_out, int out_size, void* d_ws, size_t ws_size,
                              hipStream_t stream) {
    const float* x      = (const float*)d_in[0];
    const float* W_qkv  = (const float*)d_in[1];
    const float* b_qkv  = (const float*)d_in[2];
    const float* W_proj = (const float*)d_in[3];
    const float* b_proj = (const float*)d_in[4];
    float* out = (float*)d_out;

    char* ws = (char*)d_ws;
    ushort_t* xb     = (ushort_t*)(ws);                        // 4096x1024 bf16
    ushort_t* WqkvT  = (ushort_t*)(ws + (size_t)8  * 1048576); // 3072x1024 bf16
    ushort_t* QKVb   = (ushort_t*)(ws + (size_t)14 * 1048576); // 4096x3072 bf16
    ushort_t* AO     = (ushort_t*)(ws + (size_t)38 * 1048576); // 4096x1024 bf16
    ushort_t* WprojT = (ushort_t*)(ws + (size_t)46 * 1048576); // 1024x1024 bf16

    prep<<<8192, 256, 0, stream>>>(x, xb, W_qkv, WqkvT, W_proj, WprojT);
    gemm_qkv<<<256, 512, 0, stream>>>(xb, WqkvT, b_qkv, QKVb, 3072, 1024);
    fenwick_attn<<<2048, 256, 0, stream>>>(QKVb, AO);
    gemm_proj<<<256, 256, 0, stream>>>(AO, WprojT, b_proj, out, 1024, 1024);
}